// Round 1
// baseline (1146.107 us; speedup 1.0000x reference)
//
#include <hip/hip_runtime.h>
#include <hip/hip_bf16.h>
#include <stdint.h>

// Problem constants (fixed by reference)
#define N_ROWS 131072
#define DIM    1024
#define KCL    300
#define KPAD   320      // 300 padded to 20x16 MFMA col-tiles
#define MB     64       // rows per block in gemm kernel
#define NCHUNK 16       // DIM / 64
#define QCAP   262144   // refine queue capacity (expected ~27K entries)
#define MARGIN 3.0f     // ~20 sigma of bf16 dot error

// ws layout (bytes)
#define WS_CT    0        // granule-tiled bf16 C^T: 16 chunks x 40960 B = 655360
#define WS_CNORM 655360   // padded Cnorm, 320 f32
#define WS_QC    656640   // queue counter (64 B reserved)
#define WS_CELLS 656704   // per-row atomicMin cells, 131072 x u64 = 1 MB
#define WS_QUEUE 1705280  // refine pairs, QCAP x int2 = 2 MB

typedef float  float4_ __attribute__((ext_vector_type(4)));
typedef short  short8  __attribute__((ext_vector_type(8)));

__device__ __forceinline__ unsigned short f2bf(float f) {   // RNE f32->bf16
  unsigned u = __float_as_uint(f);
  return (unsigned short)((u + 0x7fffu + ((u >> 16) & 1u)) >> 16);
}
__device__ __forceinline__ unsigned ordf(float p) {         // order-preserving f32->u32
  unsigned u = __float_as_uint(p);
  return (u & 0x80000000u) ? ~u : (u | 0x80000000u);
}
__device__ __forceinline__ float iordf(unsigned v) {
  unsigned u = (v & 0x80000000u) ? (v & 0x7fffffffu) : ~v;
  return __uint_as_float(u);
}
__device__ __forceinline__ void gll16(const void* g, void* l) {
  __builtin_amdgcn_global_load_lds(
      (const __attribute__((address_space(1))) void*)g,
      (__attribute__((address_space(3))) void*)l, 16, 0, 0);
}

// ---------------- Kernel A: prep C^T (granule-tiled bf16) + padded Cnorm ----
// Layout: elem i = (kk*320 + col)*8 + e  -> bf16(C[(kk*8+e)*300 + col]), kk=d>>3
// so each 64-d chunk tile (40960 B) is contiguous and global_load_lds-friendly.
__global__ void prep_kernel(const float* __restrict__ C, const float* __restrict__ Cn,
                            unsigned short* __restrict__ ct, float* __restrict__ cnp) {
  int i = blockIdx.x * 256 + threadIdx.x;
  if (i < KPAD * DIM) {
    int e = i & 7, col = (i >> 3) % KPAD, kk = i / (KPAD * 8);
    int d = kk * 8 + e;
    float v = (col < KCL) ? C[d * KCL + col] : 0.f;
    ct[i] = f2bf(v);
  } else if (i < KPAD * DIM + KPAD) {
    int col = i - KPAD * DIM;
    cnp[col] = (col < KCL) ? Cn[col] : 1e30f;   // pad cols never win argmin
  }
}

// ---------------- Kernel B: bf16 MFMA GEMM + fused argmin + refine enqueue --
// Block: 512 thr (8 waves), 64 rows x 320 cols. Wave grid 2x4; wave tile
// 32 rows (2 rt x 16) x 80 cols (5 ct x 16), mfma_f32_16x16x32_bf16.
// LDS: CT tile [k8][320][16B] @0 (40960) | X tile [k8][64][16B] @40960 (8192,
// XOR-swizzled rows, reused as reduction buf in epilogue) | cnorm @49152 | thr @50432
__global__ __launch_bounds__(512, 4)
void gemm_kernel(const float* __restrict__ x, const unsigned short* __restrict__ ctg,
                 const float* __restrict__ cnp, int* __restrict__ out,
                 int* __restrict__ qc, int2* __restrict__ queue) {
  __shared__ __align__(16) char smem[50688];
  const int tid  = threadIdx.x;
  const int w    = tid >> 6, lane = tid & 63;
  const int quad = lane >> 4, l16 = lane & 15;
  const int rg   = w >> 2, cg = w & 3;
  const int row0 = blockIdx.x * MB;
  const int sq   = tid & 7, srow = tid >> 3;   // staging: granule, row

  float* cnorm_s = (float*)(smem + 49152);
  if (tid < KPAD) cnorm_s[tid] = cnp[tid];

  float4_ acc[2][5];
#pragma unroll
  for (int a = 0; a < 2; ++a)
#pragma unroll
    for (int b = 0; b < 5; ++b) acc[a][b] = (float4_){0.f, 0.f, 0.f, 0.f};

  for (int c = 0; c < NCHUNK; ++c) {
    // stage Ct chunk tile (40 KB) async into LDS
    const char* cbase = (const char*)ctg + (size_t)c * 40960;
    for (int j = w; j < 40; j += 8)
      gll16(cbase + j * 1024 + lane * 16, smem + j * 1024);
    // stage x chunk: each thread one granule (8 f32 -> 8 bf16, swizzled write)
    const float* xr = x + (size_t)(row0 + srow) * DIM + c * 64 + sq * 8;
    float4_ fa = *(const float4_*)(xr);
    float4_ fb = *(const float4_*)(xr + 4);
    short8 g;
    g[0]=(short)f2bf(fa[0]); g[1]=(short)f2bf(fa[1]); g[2]=(short)f2bf(fa[2]); g[3]=(short)f2bf(fa[3]);
    g[4]=(short)f2bf(fb[0]); g[5]=(short)f2bf(fb[1]); g[6]=(short)f2bf(fb[2]); g[7]=(short)f2bf(fb[3]);
    *(short8*)(smem + 40960 + sq * 1024 + ((srow ^ (sq & 3)) * 16)) = g;
    __syncthreads();
    // compute
#pragma unroll
    for (int ks = 0; ks < 2; ++ks) {
      const int k8 = ks * 4 + quad;
      short8 af[2], bfr[5];
#pragma unroll
      for (int rt = 0; rt < 2; ++rt)
        af[rt] = *(const short8*)(smem + 40960 + k8 * 1024 +
                                  (((rg * 32 + rt * 16 + l16) ^ (quad & 3)) * 16));
#pragma unroll
      for (int ct2 = 0; ct2 < 5; ++ct2)
        bfr[ct2] = *(const short8*)(smem + k8 * 5120 +
                                    ((cg * 80 + ct2 * 16 + l16) * 16));
#pragma unroll
      for (int rt = 0; rt < 2; ++rt)
#pragma unroll
        for (int ct2 = 0; ct2 < 5; ++ct2)
          acc[rt][ct2] = __builtin_amdgcn_mfma_f32_16x16x32_bf16(
              af[rt], bfr[ct2], acc[rt][ct2], 0, 0, 0);
    }
    __syncthreads();
  }

  // ---- epilogue: p = Cnorm - 2*s; packed-key two-min argmin ----
  float p[2][5][4];
#pragma unroll
  for (int ct2 = 0; ct2 < 5; ++ct2) {
    float cn = cnorm_s[cg * 80 + ct2 * 16 + l16];
#pragma unroll
    for (int rt = 0; rt < 2; ++rt)
#pragma unroll
      for (int r = 0; r < 4; ++r)
        p[rt][ct2][r] = cn - 2.f * acc[rt][ct2][r];
  }
  unsigned long long* red = (unsigned long long*)(smem + 40960); // overlays X tile
  float* thr_s = (float*)(smem + 50432);
  for (int rt = 0; rt < 2; ++rt)
    for (int r = 0; r < 4; ++r) {
      unsigned long long b = ~0ull, s = ~0ull;
#pragma unroll
      for (int ct2 = 0; ct2 < 5; ++ct2) {
        unsigned col = (unsigned)(cg * 80 + ct2 * 16 + l16);
        unsigned long long k = ((unsigned long long)ordf(p[rt][ct2][r]) << 10) | col;
        if (k < b) { s = b; b = k; } else if (k < s) s = k;
      }
#pragma unroll
      for (int m = 1; m <= 8; m <<= 1) {           // butterfly across 16 lanes
        unsigned long long ob = __shfl_xor(b, m, 16);
        unsigned long long os = __shfl_xor(s, m, 16);
        if (ob < b) { s = (b < os) ? b : os; b = ob; } else if (ob < s) s = ob;
      }
      if (l16 == 0) {
        int row = rg * 32 + rt * 16 + quad * 4 + r;
        red[(cg * 64 + row) * 2 + 0] = b;
        red[(cg * 64 + row) * 2 + 1] = s;
      }
    }
  __syncthreads();
  if (tid < MB) {                                   // merge 4 col-groups, write out
    int row = tid;
    unsigned long long b = red[row * 2], s = red[row * 2 + 1];
#pragma unroll
    for (int cgi = 1; cgi < 4; ++cgi) {
      unsigned long long a1 = red[(cgi * 64 + row) * 2];
      unsigned long long a2 = red[(cgi * 64 + row) * 2 + 1];
      if (a1 < b) { s = (b < a2) ? b : a2; b = a1; } else if (a1 < s) s = a1;
    }
    float p1 = iordf((unsigned)(b >> 10));
    float p2 = iordf((unsigned)(s >> 10));
    out[row0 + row] = (int)(b & 1023u);
    thr_s[row] = ((p2 - p1) < MARGIN) ? (p1 + MARGIN) : -1e38f;
  }
  __syncthreads();
  // enqueue refine candidates (rare): cols with approx p < min + MARGIN
  for (int rt = 0; rt < 2; ++rt)
    for (int r = 0; r < 4; ++r) {
      int row = rg * 32 + rt * 16 + quad * 4 + r;
      float th = thr_s[row];
#pragma unroll
      for (int ct2 = 0; ct2 < 5; ++ct2)
        if (p[rt][ct2][r] < th) {
          int pos = atomicAdd(qc, 1);
          if (pos < QCAP) queue[pos] = make_int2(row0 + row, cg * 80 + ct2 * 16 + l16);
        }
    }
}

// ---------------- Kernel C: exact fp32 recompute of candidates ----------------
__global__ void refine_kernel(const float* __restrict__ x, const float* __restrict__ C,
                              const float* __restrict__ Cn, const int* __restrict__ qc,
                              const int2* __restrict__ queue,
                              unsigned long long* __restrict__ cells) {
  int gw   = (blockIdx.x * blockDim.x + threadIdx.x) >> 6;
  int lane = threadIdx.x & 63;
  int nw   = (gridDim.x * blockDim.x) >> 6;
  int count = *qc; if (count > QCAP) count = QCAP;
  for (int i = gw; i < count; i += nw) {
    int row = queue[i].x, col = queue[i].y;
    const float* xr = x + (size_t)row * DIM;
    float s = 0.f;
#pragma unroll
    for (int it = 0; it < 16; ++it) {
      int d = it * 64 + lane;
      s += xr[d] * C[d * KCL + col];
    }
#pragma unroll
    for (int m = 32; m >= 1; m >>= 1) s += __shfl_xor(s, m, 64);
    float p = Cn[col] - 2.f * s;
    unsigned long long k = ((unsigned long long)ordf(p) << 10) | (unsigned)col;
    if (lane == 0) atomicMin(&cells[row], k);
  }
}

// ---------------- Kernel D: commit refined rows -------------------------------
__global__ void final_kernel(const unsigned long long* __restrict__ cells,
                             int* __restrict__ out) {
  int i = blockIdx.x * 256 + threadIdx.x;
  if (i < N_ROWS) {
    unsigned long long v = cells[i];
    if (v != ~0ull) out[i] = (int)(v & 1023u);
  }
}

extern "C" void kernel_launch(void* const* d_in, const int* in_sizes, int n_in,
                              void* d_out, int out_size, void* d_ws, size_t ws_size,
                              hipStream_t stream) {
  const float* x  = (const float*)d_in[0];
  const float* C  = (const float*)d_in[1];
  const float* Cn = (const float*)d_in[2];
  char* ws = (char*)d_ws;
  unsigned short*      ct    = (unsigned short*)(ws + WS_CT);
  float*               cnp   = (float*)(ws + WS_CNORM);
  int*                 qc    = (int*)(ws + WS_QC);
  unsigned long long*  cells = (unsigned long long*)(ws + WS_CELLS);
  int2*                queue = (int2*)(ws + WS_QUEUE);
  int* out = (int*)d_out;

  hipMemsetAsync(qc, 0, 64, stream);
  hipMemsetAsync(cells, 0xFF, (size_t)N_ROWS * 8, stream);
  prep_kernel<<<(KPAD * DIM + KPAD + 255) / 256, 256, 0, stream>>>(C, Cn, ct, cnp);
  gemm_kernel<<<N_ROWS / MB, 512, 0, stream>>>(x, ct, cnp, out, qc, queue);
  refine_kernel<<<2048, 256, 0, stream>>>(x, C, Cn, qc, queue, cells);
  final_kernel<<<(N_ROWS + 255) / 256, 256, 0, stream>>>(cells, out);
}

// Round 2
// 1134.373 us; speedup vs baseline: 1.0103x; 1.0103x over previous
//
#include <hip/hip_runtime.h>
#include <hip/hip_bf16.h>
#include <stdint.h>

// Problem constants
#define N_ROWS 131072
#define DIM    1024
#define KCL    300
#define KPAD   320
#define QCAP   131072
#define MARGIN 4.0f     // covers bf16-trunc(x) + bf16-rne(C) approx error (~13 sigma)

// ws layout (bytes)
#define WS_CT    0        // granule-tiled bf16 C^T: 655360
#define WS_CNORM 655360   // padded Cnorm, 320 f32
#define WS_QC    656640   // queue counter
#define WS_CELLS 656704   // per-row atomicMin cells, 131072 x u64 = 1 MB
#define WS_CTF   1705280  // row-major fp32 C_T [320][1024] = 1310720
#define WS_QUEUE 3016000  // refine pairs, QCAP x int2 = 1 MB

typedef float  float4_ __attribute__((ext_vector_type(4)));
typedef short  short8  __attribute__((ext_vector_type(8)));

__device__ __forceinline__ unsigned short f2bf(float f) {   // RNE f32->bf16 (prep only)
  unsigned u = __float_as_uint(f);
  return (unsigned short)((u + 0x7fffu + ((u >> 16) & 1u)) >> 16);
}
__device__ __forceinline__ unsigned ordf(float p) {         // order-preserving f32->u32
  unsigned u = __float_as_uint(p);
  return (u & 0x80000000u) ? ~u : (u | 0x80000000u);
}
__device__ __forceinline__ float iordf(unsigned v) {
  unsigned u = (v & 0x80000000u) ? (v & 0x7fffffffu) : ~v;
  return __uint_as_float(u);
}
// pack 8 fp32 -> 8 bf16 by truncation: one v_perm_b32 per pair
__device__ __forceinline__ short8 cvt8(float4_ a, float4_ b) {
  union { unsigned u[4]; short8 s; } r;
  r.u[0] = __builtin_amdgcn_perm(__float_as_uint(a[1]), __float_as_uint(a[0]), 0x07060302u);
  r.u[1] = __builtin_amdgcn_perm(__float_as_uint(a[3]), __float_as_uint(a[2]), 0x07060302u);
  r.u[2] = __builtin_amdgcn_perm(__float_as_uint(b[1]), __float_as_uint(b[0]), 0x07060302u);
  r.u[3] = __builtin_amdgcn_perm(__float_as_uint(b[3]), __float_as_uint(b[2]), 0x07060302u);
  return r.s;
}

// ---------------- Kernel A: prep tiled bf16 C^T + fp32 C_T + padded Cnorm ----
// ct elem i = (kk*320 + col)*8 + e  -> bf16(C[(kk*8+e)*300 + col])
__global__ void prep_kernel(const float* __restrict__ C, const float* __restrict__ Cn,
                            unsigned short* __restrict__ ct, float* __restrict__ cnp,
                            float* __restrict__ ctf) {
  int i = blockIdx.x * 256 + threadIdx.x;
  if (i < KPAD * DIM) {
    int e = i & 7, col = (i >> 3) % KPAD, kk = i / (KPAD * 8);
    int d = kk * 8 + e;
    float v = (col < KCL) ? C[d * KCL + col] : 0.f;
    ct[i] = f2bf(v);
    ctf[(size_t)col * DIM + d] = v;           // coalesced-read layout for refine
  } else if (i < KPAD * DIM + KPAD) {
    int col = i - KPAD * DIM;
    cnp[col] = (col < KCL) ? Cn[col] : 1e30f;
  }
}

// ---------------- Kernel B: barrier-free register-streaming MFMA + argmin ----
// Block 256 thr = 4 waves. Wave w: 64 rows x cols [w*80, w*80+80).
// A (x rows) loaded fp32 global->VGPR, truncated to bf16 via v_perm.
// B loaded bf16 dwordx4 from pre-tiled ct (L2-resident). No __syncthreads in k-loop.
#define LOADA(c) { _Pragma("unroll") for (int rt = 0; rt < 4; ++rt) { \
    _Pragma("unroll") for (int ks = 0; ks < 2; ++ks) { \
      const float* p_ = xb + rt * 16 * DIM + (c) * 64 + ks * 32; \
      pa[rt][ks][0] = *(const float4_*)p_; \
      pa[rt][ks][1] = *(const float4_*)(p_ + 4); } } }
#define LOADB(ks, c) { _Pragma("unroll") for (int c2 = 0; c2 < 5; ++c2) { \
    pb[ks][c2] = *(const short8*)(bb + ((size_t)((c) * 8 + (ks) * 4) * KPAD + c2 * 16) * 8); } }

__global__ __launch_bounds__(256, 2)
void gemm_kernel(const float* __restrict__ x, const unsigned short* __restrict__ ctg,
                 const float* __restrict__ cnp, int* __restrict__ out,
                 int* __restrict__ qc, int2* __restrict__ queue) {
  __shared__ __align__(16) unsigned long long red[256 * 2];
  __shared__ float thr_s[64];
  const int tid = threadIdx.x;
  const int w = tid >> 6, lane = tid & 63;
  const int quad = lane >> 4, l16 = lane & 15;
  const int row0 = blockIdx.x * 64;
  const float* xb = x + (size_t)(row0 + l16) * DIM + quad * 8;
  const unsigned short* bb = ctg + ((size_t)quad * KPAD + w * 80 + l16) * 8;

  float4_ acc[4][5];
#pragma unroll
  for (int rt = 0; rt < 4; ++rt)
#pragma unroll
    for (int c2 = 0; c2 < 5; ++c2) acc[rt][c2] = (float4_){0.f, 0.f, 0.f, 0.f};

  float4_ pa[4][2][2];   // prefetched fp32 A (next chunk)
  short8  pb[2][5];      // prefetched bf16 B
  LOADA(0); LOADB(0, 0); LOADB(1, 0);

  for (int c = 0; c < 16; ++c) {
    short8 ca[2][4];
#pragma unroll
    for (int ks = 0; ks < 2; ++ks)
#pragma unroll
      for (int rt = 0; rt < 4; ++rt) ca[ks][rt] = cvt8(pa[rt][ks][0], pa[rt][ks][1]);
    if (c < 15) LOADA(c + 1);          // overlap next-chunk HBM loads with MFMAs
#pragma unroll
    for (int rt = 0; rt < 4; ++rt)
#pragma unroll
      for (int c2 = 0; c2 < 5; ++c2)
        acc[rt][c2] = __builtin_amdgcn_mfma_f32_16x16x32_bf16(ca[0][rt], pb[0][c2], acc[rt][c2], 0, 0, 0);
    if (c < 15) LOADB(0, c + 1);
#pragma unroll
    for (int rt = 0; rt < 4; ++rt)
#pragma unroll
      for (int c2 = 0; c2 < 5; ++c2)
        acc[rt][c2] = __builtin_amdgcn_mfma_f32_16x16x32_bf16(ca[1][rt], pb[1][c2], acc[rt][c2], 0, 0, 0);
    if (c < 15) LOADB(1, c + 1);
  }

  // ---- epilogue: p = Cnorm - 2*s; two-min packed-key argmin ----
  float cn[5];
#pragma unroll
  for (int c2 = 0; c2 < 5; ++c2) cn[c2] = cnp[w * 80 + c2 * 16 + l16];
  float p[4][5][4];
#pragma unroll
  for (int rt = 0; rt < 4; ++rt)
#pragma unroll
    for (int c2 = 0; c2 < 5; ++c2)
#pragma unroll
      for (int r = 0; r < 4; ++r) p[rt][c2][r] = cn[c2] - 2.f * acc[rt][c2][r];

  for (int rt = 0; rt < 4; ++rt)
    for (int r = 0; r < 4; ++r) {
      unsigned long long b = ~0ull, s = ~0ull;
#pragma unroll
      for (int c2 = 0; c2 < 5; ++c2) {
        unsigned col = (unsigned)(w * 80 + c2 * 16 + l16);
        unsigned long long k = ((unsigned long long)ordf(p[rt][c2][r]) << 10) | col;
        if (k < b) { s = b; b = k; } else if (k < s) s = k;
      }
#pragma unroll
      for (int m = 1; m <= 8; m <<= 1) {
        unsigned long long ob = __shfl_xor(b, m, 16);
        unsigned long long os = __shfl_xor(s, m, 16);
        if (ob < b) { s = (b < os) ? b : os; b = ob; } else if (ob < s) s = ob;
      }
      if (l16 == 0) {
        int row = rt * 16 + quad * 4 + r;
        red[(w * 64 + row) * 2 + 0] = b;
        red[(w * 64 + row) * 2 + 1] = s;
      }
    }
  __syncthreads();
  if (tid < 64) {
    int row = tid;
    unsigned long long b = red[row * 2], s = red[row * 2 + 1];
#pragma unroll
    for (int wi = 1; wi < 4; ++wi) {
      unsigned long long a1 = red[(wi * 64 + row) * 2];
      unsigned long long a2 = red[(wi * 64 + row) * 2 + 1];
      if (a1 < b) { s = (b < a2) ? b : a2; b = a1; } else if (a1 < s) s = a1;
    }
    float p1 = iordf((unsigned)(b >> 10));
    float p2 = iordf((unsigned)(s >> 10));
    out[row0 + row] = (int)(b & 1023u);
    thr_s[row] = ((p2 - p1) < MARGIN) ? (p1 + MARGIN) : -1e38f;
  }
  __syncthreads();
  for (int rt = 0; rt < 4; ++rt)
    for (int r = 0; r < 4; ++r) {
      int row = rt * 16 + quad * 4 + r;
      float th = thr_s[row];
#pragma unroll
      for (int c2 = 0; c2 < 5; ++c2)
        if (p[rt][c2][r] < th) {
          int pos = atomicAdd(qc, 1);
          if (pos < QCAP) queue[pos] = make_int2(row0 + row, w * 80 + c2 * 16 + l16);
        }
    }
}

// ---------------- Kernel C: exact fp32 recompute (coalesced C_T reads) -------
__global__ void refine_kernel(const float* __restrict__ x, const float* __restrict__ ctf,
                              const float* __restrict__ cnp, const int* __restrict__ qc,
                              const int2* __restrict__ queue,
                              unsigned long long* __restrict__ cells) {
  int gw   = (blockIdx.x * blockDim.x + threadIdx.x) >> 6;
  int lane = threadIdx.x & 63;
  int nw   = (gridDim.x * blockDim.x) >> 6;
  int count = *qc; if (count > QCAP) count = QCAP;
  for (int i = gw; i < count; i += nw) {
    int row = queue[i].x, col = queue[i].y;
    const float4_* xr = (const float4_*)(x + (size_t)row * DIM);
    const float4_* cr = (const float4_*)(ctf + (size_t)col * DIM);
    float s = 0.f;
#pragma unroll
    for (int it = 0; it < 4; ++it) {
      float4_ a = xr[it * 64 + lane], b = cr[it * 64 + lane];
      s += a[0] * b[0] + a[1] * b[1] + a[2] * b[2] + a[3] * b[3];
    }
#pragma unroll
    for (int m = 32; m >= 1; m >>= 1) s += __shfl_xor(s, m, 64);
    float pv = cnp[col] - 2.f * s;
    unsigned long long k = ((unsigned long long)ordf(pv) << 10) | (unsigned)col;
    if (lane == 0) atomicMin(&cells[row], k);
  }
}

// ---------------- Kernel D: commit refined rows ------------------------------
__global__ void final_kernel(const unsigned long long* __restrict__ cells,
                             int* __restrict__ out) {
  int i = blockIdx.x * 256 + threadIdx.x;
  if (i < N_ROWS) {
    unsigned long long v = cells[i];
    if (v != ~0ull) out[i] = (int)(v & 1023u);
  }
}

extern "C" void kernel_launch(void* const* d_in, const int* in_sizes, int n_in,
                              void* d_out, int out_size, void* d_ws, size_t ws_size,
                              hipStream_t stream) {
  const float* x  = (const float*)d_in[0];
  const float* C  = (const float*)d_in[1];
  const float* Cn = (const float*)d_in[2];
  char* ws = (char*)d_ws;
  unsigned short*      ct    = (unsigned short*)(ws + WS_CT);
  float*               cnp   = (float*)(ws + WS_CNORM);
  int*                 qc    = (int*)(ws + WS_QC);
  unsigned long long*  cells = (unsigned long long*)(ws + WS_CELLS);
  float*               ctf   = (float*)(ws + WS_CTF);
  int2*                queue = (int2*)(ws + WS_QUEUE);
  int* out = (int*)d_out;

  hipMemsetAsync(qc, 0, 64, stream);
  hipMemsetAsync(cells, 0xFF, (size_t)N_ROWS * 8, stream);
  prep_kernel<<<(KPAD * DIM + KPAD + 255) / 256, 256, 0, stream>>>(C, Cn, ct, cnp, ctf);
  gemm_kernel<<<N_ROWS / 64, 256, 0, stream>>>(x, ct, cnp, out, qc, queue);
  refine_kernel<<<1024, 256, 0, stream>>>(x, ctf, cnp, qc, queue, cells);
  final_kernel<<<(N_ROWS + 255) / 256, 256, 0, stream>>>(cells, out);
}